// Round 1
// baseline (779.361 us; speedup 1.0000x reference)
//
#include <hip/hip_runtime.h>
#include <hip/hip_bf16.h>

// GAT attention scores, restructured:
//   e[edge,h] = aa[h,:F]·x[row] + aa[h,F:]·x[col]   (separable projections)
//   a = segment_softmax(leakyrelu(e), by row)       (shift-invariance: no max pass)
// ws layout: s1[N*H] | s2[N*H] | ssum[N*H]  (4.8 MB fp32)

constexpr int NN = 50000;
constexpr int NE = 1600000;
constexpr int F  = 32;
constexpr int H  = 8;
constexpr float ALPHA = 0.2f;
constexpr float EPS   = 1e-12f;

__global__ __launch_bounds__(256) void node_proj_kernel(
    const float* __restrict__ x, const float* __restrict__ aa,
    float* __restrict__ s1, float* __restrict__ s2, float* __restrict__ ssum)
{
    __shared__ float aal[H * 2 * F];  // 512 floats, broadcast reads -> conflict-free
    for (int i = threadIdx.x; i < H * 2 * F; i += 256) aal[i] = aa[i];
    __syncthreads();

    int n = blockIdx.x * 256 + threadIdx.x;
    if (n >= NN) return;

    const float4* xp = reinterpret_cast<const float4*>(x + (size_t)n * F);
    float4 xv[F / 4];
#pragma unroll
    for (int i = 0; i < F / 4; ++i) xv[i] = xp[i];

    float o1[H], o2[H];
#pragma unroll
    for (int h = 0; h < H; ++h) {
        const float* a1 = &aal[h * 2 * F];
        const float* a2 = a1 + F;
        float acc1 = 0.f, acc2 = 0.f;
#pragma unroll
        for (int i = 0; i < F / 4; ++i) {
            acc1 = fmaf(a1[4*i+0], xv[i].x, acc1);
            acc1 = fmaf(a1[4*i+1], xv[i].y, acc1);
            acc1 = fmaf(a1[4*i+2], xv[i].z, acc1);
            acc1 = fmaf(a1[4*i+3], xv[i].w, acc1);
            acc2 = fmaf(a2[4*i+0], xv[i].x, acc2);
            acc2 = fmaf(a2[4*i+1], xv[i].y, acc2);
            acc2 = fmaf(a2[4*i+2], xv[i].z, acc2);
            acc2 = fmaf(a2[4*i+3], xv[i].w, acc2);
        }
        o1[h] = acc1; o2[h] = acc2;
    }

    float4* p1 = reinterpret_cast<float4*>(s1 + (size_t)n * H);
    float4* p2 = reinterpret_cast<float4*>(s2 + (size_t)n * H);
    float4* ps = reinterpret_cast<float4*>(ssum + (size_t)n * H);
    p1[0] = make_float4(o1[0], o1[1], o1[2], o1[3]);
    p1[1] = make_float4(o1[4], o1[5], o1[6], o1[7]);
    p2[0] = make_float4(o2[0], o2[1], o2[2], o2[3]);
    p2[1] = make_float4(o2[4], o2[5], o2[6], o2[7]);
    ps[0] = make_float4(0.f, 0.f, 0.f, 0.f);
    ps[1] = make_float4(0.f, 0.f, 0.f, 0.f);
}

__global__ __launch_bounds__(256) void edge_sum_kernel(
    const int* __restrict__ row, const int* __restrict__ col,
    const float* __restrict__ s1, const float* __restrict__ s2,
    float* __restrict__ ssum)
{
    int e = blockIdx.x * 256 + threadIdx.x;
    if (e >= NE) return;
    int r = row[e], c = col[e];

    const float4* p1 = reinterpret_cast<const float4*>(s1 + (size_t)r * H);
    const float4* p2 = reinterpret_cast<const float4*>(s2 + (size_t)c * H);
    float4 a0 = p1[0], a1 = p1[1];
    float4 b0 = p2[0], b1 = p2[1];

    float v[H] = {a0.x + b0.x, a0.y + b0.y, a0.z + b0.z, a0.w + b0.w,
                  a1.x + b1.x, a1.y + b1.y, a1.z + b1.z, a1.w + b1.w};

    float* base = ssum + (size_t)r * H;
#pragma unroll
    for (int h = 0; h < H; ++h) {
        float t = v[h];
        t = t > 0.f ? t : ALPHA * t;
        unsafeAtomicAdd(base + h, __expf(t));  // native global_atomic_add_f32
    }
}

__global__ __launch_bounds__(256) void edge_out_kernel(
    const int* __restrict__ row, const int* __restrict__ col,
    const float* __restrict__ s1, const float* __restrict__ s2,
    const float* __restrict__ ssum, float* __restrict__ out)
{
    int e = blockIdx.x * 256 + threadIdx.x;
    if (e >= NE) return;
    int r = row[e], c = col[e];

    const float4* p1 = reinterpret_cast<const float4*>(s1 + (size_t)r * H);
    const float4* p2 = reinterpret_cast<const float4*>(s2 + (size_t)c * H);
    const float4* ps = reinterpret_cast<const float4*>(ssum + (size_t)r * H);
    float4 a0 = p1[0], a1 = p1[1];
    float4 b0 = p2[0], b1 = p2[1];
    float4 d0 = ps[0], d1 = ps[1];

    float v[H]   = {a0.x + b0.x, a0.y + b0.y, a0.z + b0.z, a0.w + b0.w,
                    a1.x + b1.x, a1.y + b1.y, a1.z + b1.z, a1.w + b1.w};
    float den[H] = {d0.x, d0.y, d0.z, d0.w, d1.x, d1.y, d1.z, d1.w};

#pragma unroll
    for (int h = 0; h < H; ++h) {
        float t = v[h];
        t = t > 0.f ? t : ALPHA * t;
        float ex = __expf(t);                    // identical recompute to edge_sum
        out[(size_t)h * NE + e] = ex / (den[h] + EPS);  // coalesced per head
    }
}

extern "C" void kernel_launch(void* const* d_in, const int* in_sizes, int n_in,
                              void* d_out, int out_size, void* d_ws, size_t ws_size,
                              hipStream_t stream) {
    const float* x   = (const float*)d_in[0];
    const float* aa  = (const float*)d_in[1];
    const int*   row = (const int*)d_in[2];
    const int*   col = (const int*)d_in[3];
    float* out = (float*)d_out;

    float* s1   = (float*)d_ws;
    float* s2   = s1 + (size_t)NN * H;
    float* ssum = s2 + (size_t)NN * H;

    node_proj_kernel<<<(NN + 255) / 256, 256, 0, stream>>>(x, aa, s1, s2, ssum);
    edge_sum_kernel<<<NE / 256, 256, 0, stream>>>(row, col, s1, s2, ssum);
    edge_out_kernel<<<NE / 256, 256, 0, stream>>>(row, col, s1, s2, ssum, out);
}